// Round 4
// baseline (18263.278 us; speedup 1.0000x reference)
//
#include <hip/hip_runtime.h>

// ---------------------------------------------------------------------------
// BiLSTM-CRF forward loss on MI355X (gfx950).
//
// Round-3 restructure: the old 16-WG version re-streamed 768KB of weights
// from L2 per step per CU (per-CU L2 path ~153 GB/s -> >=5us/step floor;
// measured 16.3us/step, occupancy 1.5%). Now:
//   K1 lstm: 256 WGs (16 groups = dir x batch-tile, x 16 col-groups), one per
//     CU. Each wave holds its gate-tile weights in REGISTERS for all 512
//     steps. Per step: gates[16x64] via 12 MFMA, local h/c update for 16
//     hidden cols, 512B h-slice exchange with 15 peers through a
//     double-buffered global h buffer + per-step sequence flags
//     (relaxed atomics + __threadfence release/acquire).
//   Flags are zeroed by prep each launch (graph-replay & poison safe).
//   Double-buffer + "flag>=t" spin makes overwrite provably impossible
//   (writer of h(t+1) into buf[(t-1)&1] requires all peers' flag>=t+1,
//   which implies they finished reading h(t-1)).
// Contract notes (established rounds 0-3):
//   - output dtype: float32; mask input: int32.
// Workspace layout (bytes):
//   [0)         em: [2][128][512][20] f32
//   [10485760)  whh_sw: 2 x 64nt x 8kt x 64lane x 8 bf16
//   [11534336)  wih_sw: 2 x 64nt x 4kt x 64lane x 8 bf16 (K=100 pad 128)
//   [12058624)  wout_sw: 2 x 2nt x 8kt x 64lane x 8 bf16 (T=20 pad 32)
//   [12091392)  bias: [2][1024] f32
//   [12099584)  partial: [128] f32
//   [12100096)  flags: [16 gid][16 cg] int
//   [12101120)  h_glob: [2 parity][16 gid][16 rows][256 cols] bf16 (256KB)
// ---------------------------------------------------------------------------

typedef short s16x8 __attribute__((ext_vector_type(8)));
typedef float f32x4 __attribute__((ext_vector_type(4)));

#define MFMA16(a, b, c) __builtin_amdgcn_mfma_f32_16x16x32_bf16((a), (b), (c), 0, 0, 0)

__device__ __forceinline__ unsigned short f2bf(float x) {
  unsigned u = __float_as_uint(x);
  u += 0x7FFFu + ((u >> 16) & 1u);  // RNE
  return (unsigned short)(u >> 16);
}
__device__ __forceinline__ float bf2f(unsigned short h) {
  return __uint_as_float(((unsigned)h) << 16);
}
__device__ __forceinline__ float sigm(float x) {
  return __builtin_amdgcn_rcpf(1.f + __expf(-x));
}
__device__ __forceinline__ float tanh_(float x) {
  float e = __expf(2.f * x);
  return (e - 1.f) * __builtin_amdgcn_rcpf(e + 1.f);
}

// ---------------------------------------------------------------------------
// K0: weight prep (unchanged swizzle) + flag zeroing (bid==400).
// B-fragment (ntile n, ktile kt): lane l, elem e <- W[n*16+(l&15)][kt*32+(l>>4)*8+e]
// ---------------------------------------------------------------------------
__global__ __launch_bounds__(256) void prep_kernel(
    const float* __restrict__ Whh_f, const float* __restrict__ Whh_b,
    const float* __restrict__ Wih_f, const float* __restrict__ Wih_b,
    const float* __restrict__ Wout,
    const float* __restrict__ bih_f, const float* __restrict__ bhh_f,
    const float* __restrict__ bih_b, const float* __restrict__ bhh_b,
    s16x8* __restrict__ whh, s16x8* __restrict__ wih, s16x8* __restrict__ wout,
    float* __restrict__ bias, int* __restrict__ flags) {
  int bid = blockIdx.x, tid = threadIdx.x;
  if (bid < 256) {  // Whh
    int gid = bid * 256 + tid;
    int l = gid & 63, kt = (gid >> 6) & 7, n = (gid >> 9) & 63, dir = gid >> 15;
    const float* src = dir ? Whh_b : Whh_f;
    int row = n * 16 + (l & 15), k0 = kt * 32 + ((l >> 4) << 3);
    s16x8 v;
#pragma unroll
    for (int e = 0; e < 8; ++e) v[e] = (short)f2bf(src[row * 256 + k0 + e]);
    whh[gid] = v;
  } else if (bid < 384) {  // Wih
    int gid = (bid - 256) * 256 + tid;
    int l = gid & 63, kt = (gid >> 6) & 3, n = (gid >> 8) & 63, dir = gid >> 14;
    const float* src = dir ? Wih_b : Wih_f;
    int row = n * 16 + (l & 15), k0 = kt * 32 + ((l >> 4) << 3);
    s16x8 v;
#pragma unroll
    for (int e = 0; e < 8; ++e) {
      int k = k0 + e;
      v[e] = (k < 100) ? (short)f2bf(src[row * 100 + k]) : (short)0;
    }
    wih[gid] = v;
  } else if (bid < 392) {  // Wout
    int gid = (bid - 384) * 256 + tid;
    int l = gid & 63, kt = (gid >> 6) & 7, n = (gid >> 9) & 1, dir = gid >> 10;
    int colt = n * 16 + (l & 15), k0 = kt * 32 + ((l >> 4) << 3);
    s16x8 v;
#pragma unroll
    for (int e = 0; e < 8; ++e)
      v[e] = (colt < 20) ? (short)f2bf(Wout[colt * 512 + dir * 256 + k0 + e]) : (short)0;
    wout[gid] = v;
  } else if (bid < 400) {  // bias
    int idx = (bid - 392) * 256 + tid;
    if (idx < 2048) {
      int dir = idx >> 10, c = idx & 1023;
      bias[idx] = dir ? (bih_b[c] + bhh_b[c]) : (bih_f[c] + bhh_f[c]);
    }
  } else {  // flags
    if (tid < 256) flags[tid] = 0;
  }
}

// ---------------------------------------------------------------------------
// K1: BiLSTM recurrence, register-resident weights, cross-WG h exchange.
// grid = 256 (bid = cg*16 + gid; gid = dir*8 + bt), 256 threads (4 waves).
// Wave w = gate index (i,f,g,o); its 16 cols = [w*256 + cg*16, +16).
// ---------------------------------------------------------------------------
__global__ __launch_bounds__(256, 1) void lstm_kernel(
    const int* __restrict__ sent, const float* __restrict__ emb,
    const s16x8* __restrict__ whh, const s16x8* __restrict__ wih,
    const s16x8* __restrict__ wout, const float* __restrict__ bias,
    float* __restrict__ em_out, unsigned short* __restrict__ h_glob,
    int* __restrict__ flags)
{
  __shared__ unsigned short h_lds[16][264];  // h(t-1), pad to 264 (16B-aligned rows)
  __shared__ unsigned short x_lds[16][128];  // x(t), E=100 zero-padded to 128
  __shared__ unsigned short g_T[64][18];     // gates [localcol][row], bf16

  const int tid = threadIdx.x;
  const int lid = tid & 63, w = tid >> 6;
  const int cg = blockIdx.x >> 4, gid = blockIdx.x & 15;
  const int dir = gid >> 3, bt = gid & 7, r0 = bt * 16;

  const s16x8* whh_d = whh + dir * 32768;
  const s16x8* wih_d = wih + dir * 16384;
  const s16x8* wout_d = wout + dir * 1024;

  const int arow = lid & 15;
  const int ak = (lid >> 4) << 3;
  const int rb = (lid >> 4) * 4;

  // ---- persistent weights in registers ----
  s16x8 wh[8], wx[4];
  const int nt = w * 16 + cg;
#pragma unroll
  for (int kt = 0; kt < 8; ++kt) wh[kt] = whh_d[(nt * 8 + kt) * 64 + lid];
#pragma unroll
  for (int kt = 0; kt < 4; ++kt) wx[kt] = wih_d[(nt * 4 + kt) * 64 + lid];
  s16x8 wo[8];
  if (cg == 0 && w < 2) {
#pragma unroll
    for (int kt = 0; kt < 8; ++kt) wo[kt] = wout_d[(w * 8 + kt) * 64 + lid];
  }
  const float brg = bias[dir * 1024 + w * 256 + cg * 16 + arow];

  for (int i = tid; i < 16 * 264; i += 256) ((unsigned short*)h_lds)[i] = 0;
  for (int i = tid; i < 16 * 128; i += 256) ((unsigned short*)x_lds)[i] = 0;

  float creg = 0.f;
  const int urow = tid >> 4, uhc = tid & 15;  // h/c ownership: 1 value/thread

  unsigned short* hb0 = h_glob + gid * 4096;
  unsigned short* hb1 = h_glob + (16 + gid) * 4096;
  int* fl = flags + gid * 16;

  // x gather mapping: chunks 0..399 = (row 0..15) x (25 float4)
  const int rowA = tid / 25, cgA = tid - rowA * 25;
  const int tB = tid + 256;
  const int rowB = tB / 25, cgB = tB - rowB * 25;
  const bool hasB = (tid < 144);

  __syncthreads();

  for (int t = 0; t < 512; ++t) {
    const int t_eff = dir ? (511 - t) : t;

    // issue x(t) gathers early (latency overlaps the spin)
    int sidA = sent[(r0 + rowA) * 512 + t_eff];
    float4 xa = *(const float4*)&emb[sidA * 100 + cgA * 4];
    float4 xb = {0, 0, 0, 0};
    if (hasB) {
      int sidB = sent[(r0 + rowB) * 512 + t_eff];
      xb = *(const float4*)&emb[sidB * 100 + cgB * 4];
    }

    if (t > 0) {
      if (tid < 16) {
        while (__hip_atomic_load(&fl[tid], __ATOMIC_RELAXED,
                                 __HIP_MEMORY_SCOPE_AGENT) < t)
          __builtin_amdgcn_s_sleep(2);
      }
      __syncthreads();
      __threadfence();  // acquire: make peers' h(t-1) visible
      const unsigned short* src = (t & 1) ? hb0 : hb1;  // (t-1)&1 parity
      int row = tid >> 4, c0 = (tid & 15) * 16;
      uint4 va = *(const uint4*)&src[row * 256 + c0];
      uint4 vb = *(const uint4*)&src[row * 256 + c0 + 8];
      *(uint4*)&h_lds[row][c0] = va;
      *(uint4*)&h_lds[row][c0 + 8] = vb;
    }
    {  // x -> LDS (bf16)
      uint2 pk;
      pk.x = (unsigned)f2bf(xa.x) | ((unsigned)f2bf(xa.y) << 16);
      pk.y = (unsigned)f2bf(xa.z) | ((unsigned)f2bf(xa.w) << 16);
      *(uint2*)&x_lds[rowA][cgA * 4] = pk;
      if (hasB) {
        uint2 pk2;
        pk2.x = (unsigned)f2bf(xb.x) | ((unsigned)f2bf(xb.y) << 16);
        pk2.y = (unsigned)f2bf(xb.z) | ((unsigned)f2bf(xb.w) << 16);
        *(uint2*)&x_lds[rowB][cgB * 4] = pk2;
      }
    }
    __syncthreads();  // h(t-1) + x(t) staged

    // fused emissions for step t-1 (cg0, waves 0-1; h_lds holds h(t-1))
    if (cg == 0 && w < 2 && t > 0) {
      f32x4 e = {0.f, 0.f, 0.f, 0.f};
#pragma unroll
      for (int kt = 0; kt < 8; ++kt) {
        s16x8 af = *(const s16x8*)&h_lds[arow][kt * 32 + ak];
        e = MFMA16(af, wo[kt], e);
      }
      int col = w * 16 + arow;
      if (col < 20) {
        int tp = dir ? (512 - t) : (t - 1);
        int base = ((dir * 128 + r0 + rb) * 512 + tp) * 20 + col;
#pragma unroll
        for (int r = 0; r < 4; ++r) em_out[base + r * 10240] = e[r];
      }
    }

    // gate GEMM: 12 MFMA, B-frags from registers
    f32x4 acc = {brg, brg, brg, brg};
#pragma unroll
    for (int kt = 0; kt < 8; ++kt) {
      s16x8 af = *(const s16x8*)&h_lds[arow][kt * 32 + ak];
      acc = MFMA16(af, wh[kt], acc);
    }
#pragma unroll
    for (int kt = 0; kt < 4; ++kt) {
      s16x8 af = *(const s16x8*)&x_lds[arow][kt * 32 + ak];
      acc = MFMA16(af, wx[kt], acc);
    }
    {
      int colL = w * 16 + arow;
      *(unsigned*)&g_T[colL][rb] =
          (unsigned)f2bf(acc[0]) | ((unsigned)f2bf(acc[1]) << 16);
      *(unsigned*)&g_T[colL][rb + 2] =
          (unsigned)f2bf(acc[2]) | ((unsigned)f2bf(acc[3]) << 16);
    }
    __syncthreads();  // gates ready

    // h/c update: thread owns (row urow, hidden col cg*16+uhc)
    {
      float xi = bf2f(g_T[uhc][urow]);
      float xf = bf2f(g_T[16 + uhc][urow]);
      float xg = bf2f(g_T[32 + uhc][urow]);
      float xo = bf2f(g_T[48 + uhc][urow]);
      float c = sigm(xf) * creg + sigm(xi) * tanh_(xg);
      creg = c;
      unsigned short hv = f2bf(sigm(xo) * tanh_(c));
      unsigned short* dst = (t & 1) ? hb1 : hb0;
      dst[urow * 256 + cg * 16 + uhc] = hv;
    }
    __threadfence();   // release: h(t) visible before flag
    __syncthreads();   // all threads' stores+fences done
    if (tid == 0)
      __hip_atomic_store(&fl[cg], t + 1, __ATOMIC_RELAXED,
                         __HIP_MEMORY_SCOPE_AGENT);
  }

  // final emissions for t=511 (cg0 assembles h(511))
  if (cg == 0) {
    if (tid < 16) {
      while (__hip_atomic_load(&fl[tid], __ATOMIC_RELAXED,
                               __HIP_MEMORY_SCOPE_AGENT) < 512)
        __builtin_amdgcn_s_sleep(2);
    }
    __syncthreads();
    __threadfence();
    const unsigned short* src = hb1;  // 511&1 = 1
    int row = tid >> 4, c0 = (tid & 15) * 16;
    uint4 va = *(const uint4*)&src[row * 256 + c0];
    uint4 vb = *(const uint4*)&src[row * 256 + c0 + 8];
    *(uint4*)&h_lds[row][c0] = va;
    *(uint4*)&h_lds[row][c0 + 8] = vb;
    __syncthreads();
    if (w < 2) {
      f32x4 e = {0.f, 0.f, 0.f, 0.f};
#pragma unroll
      for (int kt = 0; kt < 8; ++kt) {
        s16x8 af = *(const s16x8*)&h_lds[arow][kt * 32 + ak];
        e = MFMA16(af, wo[kt], e);
      }
      int col = w * 16 + arow;
      if (col < 20) {
        int tp = dir ? 0 : 511;
        int base = ((dir * 128 + r0 + rb) * 512 + tp) * 20 + col;
#pragma unroll
        for (int r = 0; r < 4; ++r) em_out[base + r * 10240] = e[r];
      }
    }
  }
}

// ---------------------------------------------------------------------------
// K2: CRF gold score + forward algorithm. 128 blocks x 64 threads.
// ---------------------------------------------------------------------------
__global__ __launch_bounds__(64) void crf_kernel(
    const float* __restrict__ emf, const float* __restrict__ embk,
    const int* __restrict__ tags, const int* __restrict__ maski,
    const float* __restrict__ bout, const float* __restrict__ trans,
    const float* __restrict__ start_t, const float* __restrict__ end_t,
    float* __restrict__ partial) {
  __shared__ float tr[400];
  const int b = blockIdx.x, tid = threadIdx.x;
  for (int i = tid; i < 400; i += 64) tr[i] = trans[i];
  __syncthreads();

  const int tp = tid;
  const bool act = tp < 20;
  float eT[20];
  if (act) {
#pragma unroll
    for (int t2 = 0; t2 < 20; ++t2) eT[t2] = __expf(tr[t2 * 20 + tp]);
  }
  const float* ef = emf + (size_t)b * 10240;
  const float* eb = embk + (size_t)b * 10240;
  const float bo = act ? bout[tp] : 0.f;

  float a = act ? (start_t[tp] + ef[tp] + eb[tp] + bo) : -1e30f;

  float efn = 0.f, ebn = 0.f;
  if (act) { efn = ef[20 + tp]; ebn = eb[20 + tp]; }

  for (int l = 1; l < 512; ++l) {
    float e_cur = efn + ebn + bo;
    if (act && l + 1 < 512) { efn = ef[(l + 1) * 20 + tp]; ebn = eb[(l + 1) * 20 + tp]; }
    float m = a;
#pragma unroll
    for (int o = 16; o > 0; o >>= 1) m = fmaxf(m, __shfl_xor(m, o, 32));
    float p = __expf(a - m);
    float s = 0.f;
#pragma unroll
    for (int t2 = 0; t2 < 20; ++t2) s += __shfl(p, t2, 32) * eT[t2];
    float anew = m + __logf(s) + e_cur;
    int mk = maski[b * 512 + l];
    if (act && mk) a = anew;
  }
  float v = act ? (a + end_t[tp]) : -1e30f;
  float m2 = v;
#pragma unroll
  for (int o = 16; o > 0; o >>= 1) m2 = fmaxf(m2, __shfl_xor(m2, o, 32));
  float s2 = __expf(v - m2);
#pragma unroll
  for (int o = 16; o > 0; o >>= 1) s2 += __shfl_xor(s2, o, 32);
  float logZ = m2 + __logf(s2);

  const int* tg = tags + b * 512;
  float sc = 0.f;
  int cnt = 0;
  for (int l = tid; l < 512; l += 64) {
    int mk = maski[b * 512 + l];
    cnt += mk ? 1 : 0;
    if (l >= 1 && mk) {
      int cur = tg[l], prev = tg[l - 1];
      sc += tr[prev * 20 + cur] + ef[l * 20 + cur] + eb[l * 20 + cur] + bout[cur];
    }
  }
#pragma unroll
  for (int o = 32; o > 0; o >>= 1) {
    sc += __shfl_xor(sc, o, 64);
    cnt += __shfl_xor(cnt, o, 64);
  }
  if (tid == 0) {
    int t0 = tg[0];
    sc += start_t[t0] + ef[t0] + eb[t0] + bout[t0];
    sc += end_t[tg[cnt - 1]];
    partial[b] = sc - logZ;
  }
}

// ---------------------------------------------------------------------------
// K3: final reduction -> |sum|, f32 output.
// ---------------------------------------------------------------------------
__global__ __launch_bounds__(64) void final_kernel(const float* __restrict__ partial,
                                                   float* __restrict__ out) {
  int tid = threadIdx.x;
  float s = partial[tid] + partial[tid + 64];
#pragma unroll
  for (int o = 32; o > 0; o >>= 1) s += __shfl_xor(s, o, 64);
  if (tid == 0) out[0] = fabsf(s);
}

// ---------------------------------------------------------------------------
extern "C" void kernel_launch(void* const* d_in, const int* in_sizes, int n_in,
                              void* d_out, int out_size, void* d_ws, size_t ws_size,
                              hipStream_t stream) {
  const int* sent = (const int*)d_in[0];
  const int* tags = (const int*)d_in[1];
  const int* maski = (const int*)d_in[2];
  const float* emb = (const float*)d_in[3];
  const float* Wih_f = (const float*)d_in[4];
  const float* Whh_f = (const float*)d_in[5];
  const float* bih_f = (const float*)d_in[6];
  const float* bhh_f = (const float*)d_in[7];
  const float* Wih_b = (const float*)d_in[8];
  const float* Whh_b = (const float*)d_in[9];
  const float* bih_b = (const float*)d_in[10];
  const float* bhh_b = (const float*)d_in[11];
  const float* Wout = (const float*)d_in[12];
  const float* bout = (const float*)d_in[13];
  const float* trans = (const float*)d_in[14];
  const float* start_t = (const float*)d_in[15];
  const float* end_t = (const float*)d_in[16];

  char* ws = (char*)d_ws;
  float* em_base = (float*)ws;
  float* em_f = em_base;
  float* em_b = em_base + 128 * 512 * 20;
  s16x8* whh_sw = (s16x8*)(ws + 10485760);
  s16x8* wih_sw = (s16x8*)(ws + 11534336);
  s16x8* wout_sw = (s16x8*)(ws + 12058624);
  float* bias_d = (float*)(ws + 12091392);
  float* partial = (float*)(ws + 12099584);
  int* flags = (int*)(ws + 12100096);
  unsigned short* h_glob = (unsigned short*)(ws + 12101120);

  prep_kernel<<<401, 256, 0, stream>>>(Whh_f, Whh_b, Wih_f, Wih_b, Wout,
                                       bih_f, bhh_f, bih_b, bhh_b,
                                       whh_sw, wih_sw, wout_sw, bias_d, flags);
  lstm_kernel<<<256, 256, 0, stream>>>(sent, emb, whh_sw, wih_sw, wout_sw,
                                       bias_d, em_base, h_glob, flags);
  crf_kernel<<<128, 64, 0, stream>>>(em_f, em_b, tags, maski, bout, trans,
                                     start_t, end_t, partial);
  final_kernel<<<1, 64, 0, stream>>>(partial, (float*)d_out);
}

// Round 5
// 2300.597 us; speedup vs baseline: 7.9385x; 7.9385x over previous
//
#include <hip/hip_runtime.h>

// ---------------------------------------------------------------------------
// BiLSTM-CRF forward loss on MI355X (gfx950).
//
// Round-5: keep the round-4 decomposition (256 WGs = 16 groups x 16
// col-groups, weights register-resident, per-step h exchange), but make the
// exchange FENCE-FREE. Round-4's __threadfence() (x2/step/WG) = buffer_wbl2 +
// buffer_inv -> full L2 writeback+invalidate storms (WRITE_SIZE 82MB, 35us/step).
// Now:
//   - h published via RELAXED AGENT-scope 32-bit atomic stores (write-through
//     to the IF-cache coherence point; cross-XCD correct per HW atomics).
//   - ordering: atomic h stores -> __syncthreads (drains vmcnt) -> flag store.
//   - readers: relaxed atomic flag poll -> __syncthreads -> relaxed atomic
//     (uncached) coalesced word loads of the full 8KB h -> LDS.
//   - emissions computed AFTER the flag post (off the critical path).
// Contract notes (rounds 0-3): output f32; mask int32.
// Workspace layout (bytes):
//   [0)         em: [2][128][512][20] f32
//   [10485760)  whh_sw: 2 x 64nt x 8kt x 64lane x 8 bf16
//   [11534336)  wih_sw: 2 x 64nt x 4kt x 64lane x 8 bf16 (K=100 pad 128)
//   [12058624)  wout_sw: 2 x 2nt x 8kt x 64lane x 8 bf16 (T=20 pad 32)
//   [12091392)  bias: [2][1024] f32
//   [12099584)  partial: [128] f32
//   [12100096)  flags: [16 gid][16 cg] int
//   [12101120)  h_glob: [2 parity][16 gid][16 rows][256 cols] bf16 (256KB)
// ---------------------------------------------------------------------------

typedef short s16x8 __attribute__((ext_vector_type(8)));
typedef float f32x4 __attribute__((ext_vector_type(4)));

#define MFMA16(a, b, c) __builtin_amdgcn_mfma_f32_16x16x32_bf16((a), (b), (c), 0, 0, 0)
#define ATOMIC_LD(p) __hip_atomic_load((p), __ATOMIC_RELAXED, __HIP_MEMORY_SCOPE_AGENT)
#define ATOMIC_ST(p, v) \
  __hip_atomic_store((p), (v), __ATOMIC_RELAXED, __HIP_MEMORY_SCOPE_AGENT)

__device__ __forceinline__ unsigned short f2bf(float x) {
  unsigned u = __float_as_uint(x);
  u += 0x7FFFu + ((u >> 16) & 1u);  // RNE
  return (unsigned short)(u >> 16);
}
__device__ __forceinline__ float bf2f(unsigned short h) {
  return __uint_as_float(((unsigned)h) << 16);
}
__device__ __forceinline__ float sigm(float x) {
  return __builtin_amdgcn_rcpf(1.f + __expf(-x));
}
__device__ __forceinline__ float tanh_(float x) {
  float e = __expf(2.f * x);
  return (e - 1.f) * __builtin_amdgcn_rcpf(e + 1.f);
}

// ---------------------------------------------------------------------------
// K0: weight prep (swizzle) + flag zeroing (bid==400).
// B-fragment (ntile n, ktile kt): lane l, elem e <- W[n*16+(l&15)][kt*32+(l>>4)*8+e]
// ---------------------------------------------------------------------------
__global__ __launch_bounds__(256) void prep_kernel(
    const float* __restrict__ Whh_f, const float* __restrict__ Whh_b,
    const float* __restrict__ Wih_f, const float* __restrict__ Wih_b,
    const float* __restrict__ Wout,
    const float* __restrict__ bih_f, const float* __restrict__ bhh_f,
    const float* __restrict__ bih_b, const float* __restrict__ bhh_b,
    s16x8* __restrict__ whh, s16x8* __restrict__ wih, s16x8* __restrict__ wout,
    float* __restrict__ bias, int* __restrict__ flags) {
  int bid = blockIdx.x, tid = threadIdx.x;
  if (bid < 256) {  // Whh
    int gid = bid * 256 + tid;
    int l = gid & 63, kt = (gid >> 6) & 7, n = (gid >> 9) & 63, dir = gid >> 15;
    const float* src = dir ? Whh_b : Whh_f;
    int row = n * 16 + (l & 15), k0 = kt * 32 + ((l >> 4) << 3);
    s16x8 v;
#pragma unroll
    for (int e = 0; e < 8; ++e) v[e] = (short)f2bf(src[row * 256 + k0 + e]);
    whh[gid] = v;
  } else if (bid < 384) {  // Wih
    int gid = (bid - 256) * 256 + tid;
    int l = gid & 63, kt = (gid >> 6) & 3, n = (gid >> 8) & 63, dir = gid >> 14;
    const float* src = dir ? Wih_b : Wih_f;
    int row = n * 16 + (l & 15), k0 = kt * 32 + ((l >> 4) << 3);
    s16x8 v;
#pragma unroll
    for (int e = 0; e < 8; ++e) {
      int k = k0 + e;
      v[e] = (k < 100) ? (short)f2bf(src[row * 100 + k]) : (short)0;
    }
    wih[gid] = v;
  } else if (bid < 392) {  // Wout
    int gid = (bid - 384) * 256 + tid;
    int l = gid & 63, kt = (gid >> 6) & 7, n = (gid >> 9) & 1, dir = gid >> 10;
    int colt = n * 16 + (l & 15), k0 = kt * 32 + ((l >> 4) << 3);
    s16x8 v;
#pragma unroll
    for (int e = 0; e < 8; ++e)
      v[e] = (colt < 20) ? (short)f2bf(Wout[colt * 512 + dir * 256 + k0 + e]) : (short)0;
    wout[gid] = v;
  } else if (bid < 400) {  // bias
    int idx = (bid - 392) * 256 + tid;
    if (idx < 2048) {
      int dir = idx >> 10, c = idx & 1023;
      bias[idx] = dir ? (bih_b[c] + bhh_b[c]) : (bih_f[c] + bhh_f[c]);
    }
  } else {  // flags
    if (tid < 256) flags[tid] = 0;
  }
}

// ---------------------------------------------------------------------------
// K1: BiLSTM recurrence, register-resident weights, fence-free h exchange.
// grid = 256 (bid = cg*16 + gid; gid = dir*8 + bt), 256 threads (4 waves).
// Wave w = gate index (i,f,g,o); its 16 cols = [w*256 + cg*16, +16).
// ---------------------------------------------------------------------------
__global__ __launch_bounds__(256, 1) void lstm_kernel(
    const int* __restrict__ sent, const float* __restrict__ emb,
    const s16x8* __restrict__ whh, const s16x8* __restrict__ wih,
    const s16x8* __restrict__ wout, const float* __restrict__ bias,
    float* __restrict__ em_out, unsigned short* __restrict__ h_glob,
    int* __restrict__ flags)
{
  __shared__ unsigned short h_lds[16][264];   // h(t-1), padded rows
  __shared__ unsigned short x_lds[16][128];   // x(t), E=100 zero-padded
  __shared__ unsigned short g_T[64][18];      // gates [localcol][row]
  __shared__ unsigned short hstage[16][16];   // own h(t) slice staging

  const int tid = threadIdx.x;
  const int lid = tid & 63, w = tid >> 6;
  const int cg = blockIdx.x >> 4, gid = blockIdx.x & 15;
  const int dir = gid >> 3, bt = gid & 7, r0 = bt * 16;

  const s16x8* whh_d = whh + dir * 32768;
  const s16x8* wih_d = wih + dir * 16384;
  const s16x8* wout_d = wout + dir * 1024;

  const int arow = lid & 15;
  const int ak = (lid >> 4) << 3;
  const int rb = (lid >> 4) * 4;

  // ---- persistent weights in registers ----
  s16x8 wh[8], wx[4];
  const int nt = w * 16 + cg;
#pragma unroll
  for (int kt = 0; kt < 8; ++kt) wh[kt] = whh_d[(nt * 8 + kt) * 64 + lid];
#pragma unroll
  for (int kt = 0; kt < 4; ++kt) wx[kt] = wih_d[(nt * 4 + kt) * 64 + lid];
  s16x8 wo[8];
  if (cg == 0 && w < 2) {
#pragma unroll
    for (int kt = 0; kt < 8; ++kt) wo[kt] = wout_d[(w * 8 + kt) * 64 + lid];
  }
  const float brg = bias[dir * 1024 + w * 256 + cg * 16 + arow];

  for (int i = tid; i < 16 * 264; i += 256) ((unsigned short*)h_lds)[i] = 0;
  for (int i = tid; i < 16 * 128; i += 256) ((unsigned short*)x_lds)[i] = 0;

  float creg = 0.f;
  const int urow = tid >> 4, uhc = tid & 15;

  unsigned* hb0 = (unsigned*)(h_glob + gid * 4096);         // parity 0
  unsigned* hb1 = (unsigned*)(h_glob + (16 + gid) * 4096);  // parity 1
  int* fl = flags + gid * 16;

  // x gather mapping: chunks 0..399 = (row 0..15) x (25 float4)
  const int rowA = tid / 25, cgA = tid - rowA * 25;
  const int tB = tid + 256;
  const int rowB = tB / 25, cgB = tB - rowB * 25;
  const bool hasB = (tid < 144);

  __syncthreads();

  for (int t = 0; t < 512; ++t) {
    const int t_eff = dir ? (511 - t) : t;

    // issue x(t) gathers early (overlap the poll)
    int sidA = sent[(r0 + rowA) * 512 + t_eff];
    float4 xa = *(const float4*)&emb[sidA * 100 + cgA * 4];
    float4 xb = {0, 0, 0, 0};
    if (hasB) {
      int sidB = sent[(r0 + rowB) * 512 + t_eff];
      xb = *(const float4*)&emb[sidB * 100 + cgB * 4];
    }

    if (t > 0) {
      if (tid < 16) {
        while (ATOMIC_LD(&fl[tid]) < t) __builtin_amdgcn_s_sleep(2);
      }
      __syncthreads();  // syncA: flags observed; prev-iter h_lds readers done
      unsigned* srcw = (t & 1) ? hb0 : hb1;  // parity (t-1)&1
#pragma unroll
      for (int i = 0; i < 8; ++i) {
        int wi = i * 256 + tid;  // word index 0..2047, coalesced
        unsigned wv = ATOMIC_LD(&srcw[wi]);
        *(unsigned*)&h_lds[wi >> 7][(wi & 127) * 2] = wv;
      }
    }
    {  // x -> LDS (bf16)
      uint2 pk;
      pk.x = (unsigned)f2bf(xa.x) | ((unsigned)f2bf(xa.y) << 16);
      pk.y = (unsigned)f2bf(xa.z) | ((unsigned)f2bf(xa.w) << 16);
      *(uint2*)&x_lds[rowA][cgA * 4] = pk;
      if (hasB) {
        uint2 pk2;
        pk2.x = (unsigned)f2bf(xb.x) | ((unsigned)f2bf(xb.y) << 16);
        pk2.y = (unsigned)f2bf(xb.z) | ((unsigned)f2bf(xb.w) << 16);
        *(uint2*)&x_lds[rowB][cgB * 4] = pk2;
      }
    }
    __syncthreads();  // syncB: h(t-1) + x(t) staged

    // gate GEMM: 12 MFMA, B-frags in registers
    f32x4 acc = {brg, brg, brg, brg};
#pragma unroll
    for (int kt = 0; kt < 8; ++kt) {
      s16x8 af = *(const s16x8*)&h_lds[arow][kt * 32 + ak];
      acc = MFMA16(af, wh[kt], acc);
    }
#pragma unroll
    for (int kt = 0; kt < 4; ++kt) {
      s16x8 af = *(const s16x8*)&x_lds[arow][kt * 32 + ak];
      acc = MFMA16(af, wx[kt], acc);
    }
    {
      int colL = w * 16 + arow;
      *(unsigned*)&g_T[colL][rb] =
          (unsigned)f2bf(acc[0]) | ((unsigned)f2bf(acc[1]) << 16);
      *(unsigned*)&g_T[colL][rb + 2] =
          (unsigned)f2bf(acc[2]) | ((unsigned)f2bf(acc[3]) << 16);
    }
    __syncthreads();  // syncC: gates ready

    // h/c update: thread owns (row urow, hidden col cg*16+uhc)
    {
      float xi = bf2f(g_T[uhc][urow]);
      float xf = bf2f(g_T[16 + uhc][urow]);
      float xg = bf2f(g_T[32 + uhc][urow]);
      float xo = bf2f(g_T[48 + uhc][urow]);
      float c = sigm(xf) * creg + sigm(xi) * tanh_(xg);
      creg = c;
      hstage[urow][uhc] = f2bf(sigm(xo) * tanh_(c));
    }
    __syncthreads();  // syncD: hstage ready

    // publish own 16x16 h-slice: 128 packed words, write-through atomics
    if (tid < 128) {
      int row = tid >> 3, cp = tid & 7;
      unsigned pk2 =
          (unsigned)hstage[row][cp * 2] | ((unsigned)hstage[row][cp * 2 + 1] << 16);
      unsigned* dstw = (t & 1) ? hb1 : hb0;  // parity t&1
      ATOMIC_ST(&dstw[row * 128 + cg * 8 + cp], pk2);
    }
    __syncthreads();  // syncE: drains vmcnt -> h stores at coherence point
    if (tid == 0) ATOMIC_ST(&fl[cg], t + 1);

    // fused emissions for step t-1 (cg0 waves 0-1) — AFTER flag, off the
    // critical path; h_lds stays valid until next iter's post-syncA staging.
    if (cg == 0 && w < 2 && t > 0) {
      f32x4 e = {0.f, 0.f, 0.f, 0.f};
#pragma unroll
      for (int kt = 0; kt < 8; ++kt) {
        s16x8 af = *(const s16x8*)&h_lds[arow][kt * 32 + ak];
        e = MFMA16(af, wo[kt], e);
      }
      int col = w * 16 + arow;
      if (col < 20) {
        int tp = dir ? (512 - t) : (t - 1);
        int base = ((dir * 128 + r0 + rb) * 512 + tp) * 20 + col;
#pragma unroll
        for (int r = 0; r < 4; ++r) em_out[base + r * 10240] = e[r];
      }
    }
  }

  // final emissions for t=511 (cg0 assembles h(511) from parity 1)
  if (cg == 0) {
    if (tid < 16) {
      while (ATOMIC_LD(&fl[tid]) < 512) __builtin_amdgcn_s_sleep(2);
    }
    __syncthreads();
#pragma unroll
    for (int i = 0; i < 8; ++i) {
      int wi = i * 256 + tid;
      unsigned wv = ATOMIC_LD(&hb1[wi]);
      *(unsigned*)&h_lds[wi >> 7][(wi & 127) * 2] = wv;
    }
    __syncthreads();
    if (w < 2) {
      f32x4 e = {0.f, 0.f, 0.f, 0.f};
#pragma unroll
      for (int kt = 0; kt < 8; ++kt) {
        s16x8 af = *(const s16x8*)&h_lds[arow][kt * 32 + ak];
        e = MFMA16(af, wo[kt], e);
      }
      int col = w * 16 + arow;
      if (col < 20) {
        int tp = dir ? 0 : 511;
        int base = ((dir * 128 + r0 + rb) * 512 + tp) * 20 + col;
#pragma unroll
        for (int r = 0; r < 4; ++r) em_out[base + r * 10240] = e[r];
      }
    }
  }
}

// ---------------------------------------------------------------------------
// K2: CRF gold score + forward algorithm. 128 blocks x 64 threads.
// ---------------------------------------------------------------------------
__global__ __launch_bounds__(64) void crf_kernel(
    const float* __restrict__ emf, const float* __restrict__ embk,
    const int* __restrict__ tags, const int* __restrict__ maski,
    const float* __restrict__ bout, const float* __restrict__ trans,
    const float* __restrict__ start_t, const float* __restrict__ end_t,
    float* __restrict__ partial) {
  __shared__ float tr[400];
  const int b = blockIdx.x, tid = threadIdx.x;
  for (int i = tid; i < 400; i += 64) tr[i] = trans[i];
  __syncthreads();

  const int tp = tid;
  const bool act = tp < 20;
  float eT[20];
  if (act) {
#pragma unroll
    for (int t2 = 0; t2 < 20; ++t2) eT[t2] = __expf(tr[t2 * 20 + tp]);
  }
  const float* ef = emf + (size_t)b * 10240;
  const float* eb = embk + (size_t)b * 10240;
  const float bo = act ? bout[tp] : 0.f;

  float a = act ? (start_t[tp] + ef[tp] + eb[tp] + bo) : -1e30f;

  float efn = 0.f, ebn = 0.f;
  if (act) { efn = ef[20 + tp]; ebn = eb[20 + tp]; }

  for (int l = 1; l < 512; ++l) {
    float e_cur = efn + ebn + bo;
    if (act && l + 1 < 512) { efn = ef[(l + 1) * 20 + tp]; ebn = eb[(l + 1) * 20 + tp]; }
    float m = a;
#pragma unroll
    for (int o = 16; o > 0; o >>= 1) m = fmaxf(m, __shfl_xor(m, o, 32));
    float p = __expf(a - m);
    float s = 0.f;
#pragma unroll
    for (int t2 = 0; t2 < 20; ++t2) s += __shfl(p, t2, 32) * eT[t2];
    float anew = m + __logf(s) + e_cur;
    int mk = maski[b * 512 + l];
    if (act && mk) a = anew;
  }
  float v = act ? (a + end_t[tp]) : -1e30f;
  float m2 = v;
#pragma unroll
  for (int o = 16; o > 0; o >>= 1) m2 = fmaxf(m2, __shfl_xor(m2, o, 32));
  float s2 = __expf(v - m2);
#pragma unroll
  for (int o = 16; o > 0; o >>= 1) s2 += __shfl_xor(s2, o, 32);
  float logZ = m2 + __logf(s2);

  const int* tg = tags + b * 512;
  float sc = 0.f;
  int cnt = 0;
  for (int l = tid; l < 512; l += 64) {
    int mk = maski[b * 512 + l];
    cnt += mk ? 1 : 0;
    if (l >= 1 && mk) {
      int cur = tg[l], prev = tg[l - 1];
      sc += tr[prev * 20 + cur] + ef[l * 20 + cur] + eb[l * 20 + cur] + bout[cur];
    }
  }
#pragma unroll
  for (int o = 32; o > 0; o >>= 1) {
    sc += __shfl_xor(sc, o, 64);
    cnt += __shfl_xor(cnt, o, 64);
  }
  if (tid == 0) {
    int t0 = tg[0];
    sc += start_t[t0] + ef[t0] + eb[t0] + bout[t0];
    sc += end_t[tg[cnt - 1]];
    partial[b] = sc - logZ;
  }
}

// ---------------------------------------------------------------------------
// K3: final reduction -> |sum|, f32 output.
// ---------------------------------------------------------------------------
__global__ __launch_bounds__(64) void final_kernel(const float* __restrict__ partial,
                                                   float* __restrict__ out) {
  int tid = threadIdx.x;
  float s = partial[tid] + partial[tid + 64];
#pragma unroll
  for (int o = 32; o > 0; o >>= 1) s += __shfl_xor(s, o, 64);
  if (tid == 0) out[0] = fabsf(s);
}

// ---------------------------------------------------------------------------
extern "C" void kernel_launch(void* const* d_in, const int* in_sizes, int n_in,
                              void* d_out, int out_size, void* d_ws, size_t ws_size,
                              hipStream_t stream) {
  const int* sent = (const int*)d_in[0];
  const int* tags = (const int*)d_in[1];
  const int* maski = (const int*)d_in[2];
  const float* emb = (const float*)d_in[3];
  const float* Wih_f = (const float*)d_in[4];
  const float* Whh_f = (const float*)d_in[5];
  const float* bih_f = (const float*)d_in[6];
  const float* bhh_f = (const float*)d_in[7];
  const float* Wih_b = (const float*)d_in[8];
  const float* Whh_b = (const float*)d_in[9];
  const float* bih_b = (const float*)d_in[10];
  const float* bhh_b = (const float*)d_in[11];
  const float* Wout = (const float*)d_in[12];
  const float* bout = (const float*)d_in[13];
  const float* trans = (const float*)d_in[14];
  const float* start_t = (const float*)d_in[15];
  const float* end_t = (const float*)d_in[16];

  char* ws = (char*)d_ws;
  float* em_base = (float*)ws;
  float* em_f = em_base;
  float* em_b = em_base + 128 * 512 * 20;
  s16x8* whh_sw = (s16x8*)(ws + 10485760);
  s16x8* wih_sw = (s16x8*)(ws + 11534336);
  s16x8* wout_sw = (s16x8*)(ws + 12058624);
  float* bias_d = (float*)(ws + 12091392);
  float* partial = (float*)(ws + 12099584);
  int* flags = (int*)(ws + 12100096);
  unsigned short* h_glob = (unsigned short*)(ws + 12101120);

  prep_kernel<<<401, 256, 0, stream>>>(Whh_f, Whh_b, Wih_f, Wih_b, Wout,
                                       bih_f, bhh_f, bih_b, bhh_b,
                                       whh_sw, wih_sw, wout_sw, bias_d, flags);
  lstm_kernel<<<256, 256, 0, stream>>>(sent, emb, whh_sw, wih_sw, wout_sw,
                                       bias_d, em_base, h_glob, flags);
  crf_kernel<<<128, 64, 0, stream>>>(em_f, em_b, tags, maski, bout, trans,
                                     start_t, end_t, partial);
  final_kernel<<<1, 64, 0, stream>>>(partial, (float*)d_out);
}